// Round 5
// baseline (89.657 us; speedup 1.0000x reference)
//
#include <hip/hip_runtime.h>

#define BATCH  512
#define K_OPS  16
#define D2     128
#define TSTEPS 64
#define NSLAB  (BATCH * TSTEPS)   // 32768 slabs of 16*128 floats (8 KB)
#define CHAINB 512                // chain blocks in k_prop
#define ZEROB  2048               // zero blocks in k_prop

typedef float vf4 __attribute__((ext_vector_type(4)));

__device__ inline int argmax16(const float* __restrict__ ub) {
    float m = ub[0]; int lab = 0;
    #pragma unroll
    for (int j = 1; j < K_OPS; ++j) {
        const float v = ub[j];
        if (v > m) { m = v; lab = j; }
    }
    return lab;
}

// ---------------------------------------------------------------------------
// K1: labels (blocks 0..15) + fused X = S@sym(H) + 10 Taylor orders.
// 256 blocks = 16 ops x 16 row-strips (8 rows each).
// ---------------------------------------------------------------------------
__global__ __launch_bounds__(256) void k_taylor(
    const float* __restrict__ H, const float* __restrict__ u,
    float* __restrict__ ACC, int* __restrict__ labels)
{
    __shared__ float Hs[D2][D2 + 1];
    __shared__ float Xs[D2][D2];
    __shared__ float PsT[D2][12];

    const int bid = blockIdx.x, tid = threadIdx.x;

    // labels for the zero blocks of k_prop (16 blocks x 32 threads)
    if (bid < 16 && tid < 32) {
        const int b = bid * 32 + tid;
        labels[b] = argmax16(u + b * K_OPS);
    }

    const int k  = bid >> 4;
    const int r0 = (bid & 15) * 8;
    const float* Hk = H + k * D2 * D2;

    for (int idx = tid; idx < D2 * D2; idx += 256)
        Hs[idx >> 7][idx & 127] = Hk[idx];
    __syncthreads();

    // X[i][j] = sgn(i) * 0.5 * (H[i^64][j] + H[j][i^64])
    for (int idx = tid; idx < D2 * D2; idx += 256) {
        const int i = idx >> 7, j = idx & 127;
        const int i2 = i ^ 64;
        const float sgn = (i < 64) ? 0.5f : -0.5f;
        Xs[i][j] = sgn * (Hs[i2][j] + Hs[j][i2]);
    }
    __syncthreads();

    const int c  = tid & 127;
    const int rg = tid >> 7;

    float acc[4];
    {
        float4 iv;
        float* ivp = (float*)&iv;
        #pragma unroll
        for (int rr = 0; rr < 4; ++rr) {
            const int row = r0 + rg * 4 + rr;
            const float xv = Xs[row][c];
            acc[rr] = xv + ((row == c) ? 1.0f : 0.0f);   // I + X
            ivp[rr] = xv;
        }
        *(float4*)&PsT[c][rg * 4] = iv;                   // P = X (transposed)
    }
    __syncthreads();

    #pragma unroll
    for (int it = 2; it <= 10; ++it) {
        const float inv = 1.0f / (float)it;
        float nv[4] = {0.f, 0.f, 0.f, 0.f};
        #pragma unroll 4
        for (int j = 0; j < D2; ++j) {
            const float xv = Xs[j][c];
            const float4 pv = *(const float4*)&PsT[j][rg * 4];
            nv[0] = fmaf(pv.x, xv, nv[0]);
            nv[1] = fmaf(pv.y, xv, nv[1]);
            nv[2] = fmaf(pv.z, xv, nv[2]);
            nv[3] = fmaf(pv.w, xv, nv[3]);
        }
        #pragma unroll
        for (int rr = 0; rr < 4; ++rr) { nv[rr] *= inv; acc[rr] += nv[rr]; }
        __syncthreads();
        *(float4*)&PsT[c][rg * 4] = make_float4(nv[0], nv[1], nv[2], nv[3]);
        __syncthreads();
    }

    float* Ak = ACC + k * D2 * D2;
    #pragma unroll
    for (int rr = 0; rr < 4; ++rr)
        Ak[(r0 + rg * 4 + rr) * D2 + c] = acc[rr];
}

// ---------------------------------------------------------------------------
// K2: blocks 0..511 = per-batch chains (128 thr, outputs buffered in LDS so
// every __syncthreads drains only lgkm — no vmem in flight); blocks 512+ =
// barrier-free zero blocks streaming at write BW, skipping label channels.
// ---------------------------------------------------------------------------
__global__ __launch_bounds__(128) void k_prop(
    const float* __restrict__ s_in, const float* __restrict__ ACC,
    const int* __restrict__ labels, float* __restrict__ out)
{
    const int bid = blockIdx.x, tid = threadIdx.x;

    if (bid >= CHAINB) {
        // ---- zero path: no barriers, free-running store stream ----
        const int z = bid - CHAINB;
        const vf4 zv = {0.f, 0.f, 0.f, 0.f};
        for (int slab = z; slab < NSLAB; slab += ZEROB) {
            const int lab = labels[slab >> 6];
            vf4* p = (vf4*)(out + (size_t)slab * 2048);
            #pragma unroll
            for (int q = 0; q < 4; ++q) {
                const int slot = tid + q * 128;
                if ((slot >> 5) != lab)
                    __builtin_nontemporal_store(zv, p + slot);
            }
        }
        return;
    }

    // ---- chain path: one batch per block, thread i owns row i ----
    __shared__ float s_lds[D2];
    __shared__ float out_lds[TSTEPS][D2];   // 32 KB trajectory buffer

    const int b = bid, i = tid;
    const int lab = labels[b];

    float row[D2];
    const float4* rowp = (const float4*)(ACC + (lab * D2 + i) * D2);
    #pragma unroll
    for (int jj = 0; jj < 32; ++jj) {
        const float4 rv = rowp[jj];
        row[4 * jj + 0] = rv.x; row[4 * jj + 1] = rv.y;
        row[4 * jj + 2] = rv.z; row[4 * jj + 3] = rv.w;
    }

    float sval = s_in[(b * K_OPS + lab) * D2 + i];
    s_lds[i] = sval;
    out_lds[0][i] = sval;
    __syncthreads();

    for (int t = 1; t < TSTEPS; ++t) {
        float acc = 0.f;
        const float4* s4 = (const float4*)s_lds;
        #pragma unroll
        for (int jj = 0; jj < 32; ++jj) {
            const float4 sv = s4[jj];
            acc = fmaf(row[4 * jj + 0], sv.x, acc);
            acc = fmaf(row[4 * jj + 1], sv.y, acc);
            acc = fmaf(row[4 * jj + 2], sv.z, acc);
            acc = fmaf(row[4 * jj + 3], sv.w, acc);
        }
        __syncthreads();              // all reads of s_lds done (lgkm only)
        s_lds[i] = acc;
        out_lds[t][i] = acc;
        __syncthreads();              // new state visible (lgkm only)
        sval = acc;
    }

    // ---- bulk store: 32 KB coalesced, fire-and-forget ----
    const float* ol = &out_lds[0][0];
    float* ob = out + ((size_t)b * TSTEPS * K_OPS + lab) * D2;
    #pragma unroll
    for (int q = 0; q < 16; ++q) {
        const int s  = tid + q * 128;        // 0..2047 float4 slots
        const int t  = s >> 5;
        const int c4 = s & 31;
        const vf4 v = *(const vf4*)(ol + s * 4);
        __builtin_nontemporal_store(v, (vf4*)(ob + (size_t)t * K_OPS * D2) + c4);
    }
}

extern "C" void kernel_launch(void* const* d_in, const int* in_sizes, int n_in,
                              void* d_out, int out_size, void* d_ws, size_t ws_size,
                              hipStream_t stream) {
    const float* u_t = (const float*)d_in[0];   // [512,16]
    const float* s_t = (const float*)d_in[1];   // [512,16,128]
    const float* H   = (const float*)d_in[2];   // [16,128,128]

    float* out    = (float*)d_out;
    float* Aw     = (float*)d_ws;                       // [16,128,128] = 1 MB
    int*   labels = (int*)(Aw + K_OPS * D2 * D2);       // [512]

    hipLaunchKernelGGL(k_taylor, dim3(256), dim3(256), 0, stream,
                       H, u_t, Aw, labels);
    hipLaunchKernelGGL(k_prop, dim3(CHAINB + ZEROB), dim3(128), 0, stream,
                       s_t, Aw, labels, out);
}

// Round 6
// 78.959 us; speedup vs baseline: 1.1355x; 1.1355x over previous
//
#include <hip/hip_runtime.h>

#define BATCH  512
#define K_OPS  16
#define D2     128
#define TSTEPS 64
#define NSLAB  (BATCH * TSTEPS)   // 32768 slabs of 16*128 floats (8 KB)
#define CHAINB 512                // chain blocks in k_prop
#define ZEROB  2048               // zero blocks in k_prop

typedef float vf4 __attribute__((ext_vector_type(4)));

__device__ inline int argmax16(const float* __restrict__ ub) {
    float m = ub[0]; int lab = 0;
    #pragma unroll
    for (int j = 1; j < K_OPS; ++j) {
        const float v = ub[j];
        if (v > m) { m = v; lab = j; }
    }
    return lab;
}

// ---------------------------------------------------------------------------
// K1: labels + fused X = S@sym(H) + 10 Taylor orders, v2.
// 256 blocks = 16 ops x 16 row-strips (8 rows). 256 threads = 4 jg-groups
// (j-split) x 2 rg x 32 cg; each thread owns a 4x4 tile of the strip.
// Per j: 1 b128 P-broadcast + 1 b128 X-read + 16 FMA  (2.1x fewer LDS
// issues than v1's per-j b32+b128 at 4 output elems/thread).
// ---------------------------------------------------------------------------
__global__ __launch_bounds__(256) void k_taylor(
    const float* __restrict__ H, const float* __restrict__ u,
    float* __restrict__ ACC, int* __restrict__ labels)
{
    __shared__ union {
        float Hs[D2][132];        // staging for X build (dead after build)
        float Red[3][64][20];     // jg-partial reduction buffer (pad 20)
    } U;
    __shared__ float Xs[D2][132]; // padded: 528B rows, 16B-aligned
    __shared__ float PsT[D2][12]; // PsT[c][r] = P[r0+r][c]

    const int bid = blockIdx.x, tid = threadIdx.x;

    // labels for k_prop's zero blocks (16 blocks x 32 threads)
    if (bid < 16 && tid < 32) {
        const int b = bid * 32 + tid;
        labels[b] = argmax16(u + b * K_OPS);
    }

    const int k  = bid >> 4;
    const int r0 = (bid & 15) * 8;
    const float* Hk = H + k * D2 * D2;

    // ---- stage H into padded LDS (float4) ----
    #pragma unroll
    for (int mm = 0; mm < 16; ++mm) {
        const int idx4 = tid + mm * 256;            // 0..4095 float4s
        const float4 v = *(const float4*)&Hk[idx4 * 4];
        const int row = idx4 >> 5, col = (idx4 & 31) * 4;
        *(float4*)&U.Hs[row][col] = v;
    }
    __syncthreads();

    // ---- X[i][j] = sgn(i)*0.5*(H[i^64][j] + H[j][i^64]) ----
    // column reads Hs[j][i2]: padded stride 132 -> bank (j+i2)%32, conflict-free
    #pragma unroll 4
    for (int m = 0; m < 64; ++m) {
        const int idx = tid + m * 256;
        const int i = idx >> 7, j = idx & 127;
        const int i2 = i ^ 64;
        const float sgn = (i < 64) ? 0.5f : -0.5f;
        Xs[i][j] = sgn * (U.Hs[i2][j] + U.Hs[j][i2]);
    }
    __syncthreads();

    const int jg = tid >> 6;            // 0..3  (wave index)
    const int rg = (tid >> 5) & 1;      // 0..1
    const int cg = tid & 31;            // 0..31

    // ---- init: P^1 = X (transposed strip into PsT); acc = I + X ----
    {
        const int c = tid & 127, rh = tid >> 7;
        float4 v;
        v.x = Xs[r0 + rh * 4 + 0][c];
        v.y = Xs[r0 + rh * 4 + 1][c];
        v.z = Xs[r0 + rh * 4 + 2][c];
        v.w = Xs[r0 + rh * 4 + 3][c];
        *(float4*)&PsT[c][rh * 4] = v;
    }
    float acc[4][4];
    if (jg == 0) {
        #pragma unroll
        for (int rr = 0; rr < 4; ++rr) {
            const int row = r0 + rg * 4 + rr;
            const float4 x = *(const float4*)&Xs[row][cg * 4];
            acc[rr][0] = x.x + ((row == cg * 4 + 0) ? 1.0f : 0.0f);
            acc[rr][1] = x.y + ((row == cg * 4 + 1) ? 1.0f : 0.0f);
            acc[rr][2] = x.z + ((row == cg * 4 + 2) ? 1.0f : 0.0f);
            acc[rr][3] = x.w + ((row == cg * 4 + 3) ? 1.0f : 0.0f);
        }
    }
    __syncthreads();

    // ---- 9 remaining Taylor orders ----
    for (int it = 2; it <= 10; ++it) {
        float nv[4][4] = {{0.f,0.f,0.f,0.f},{0.f,0.f,0.f,0.f},
                          {0.f,0.f,0.f,0.f},{0.f,0.f,0.f,0.f}};
        #pragma unroll 8
        for (int m = 0; m < 32; ++m) {
            const int j = (m << 2) | jg;
            const float4 pv = *(const float4*)&PsT[j][rg * 4];
            const float4 xv = *(const float4*)&Xs[j][cg * 4];
            const float p[4] = {pv.x, pv.y, pv.z, pv.w};
            const float x[4] = {xv.x, xv.y, xv.z, xv.w};
            #pragma unroll
            for (int rr = 0; rr < 4; ++rr)
                #pragma unroll
                for (int cc = 0; cc < 4; ++cc)
                    nv[rr][cc] = fmaf(p[rr], x[cc], nv[rr][cc]);
        }
        if (jg != 0) {
            float* rb = U.Red[jg - 1][rg * 32 + cg];
            #pragma unroll
            for (int rr = 0; rr < 4; ++rr)
                *(float4*)&rb[rr * 4] =
                    make_float4(nv[rr][0], nv[rr][1], nv[rr][2], nv[rr][3]);
        }
        __syncthreads();
        if (jg == 0) {
            #pragma unroll
            for (int g = 0; g < 3; ++g) {
                const float* rb = U.Red[g][rg * 32 + cg];
                #pragma unroll
                for (int rr = 0; rr < 4; ++rr) {
                    const float4 p = *(const float4*)&rb[rr * 4];
                    nv[rr][0] += p.x; nv[rr][1] += p.y;
                    nv[rr][2] += p.z; nv[rr][3] += p.w;
                }
            }
            const float inv = 1.0f / (float)it;
            #pragma unroll
            for (int rr = 0; rr < 4; ++rr)
                #pragma unroll
                for (int cc = 0; cc < 4; ++cc) {
                    nv[rr][cc] *= inv;
                    acc[rr][cc] += nv[rr][cc];
                }
            // P_new into PsT (column-major strip)
            #pragma unroll
            for (int cc = 0; cc < 4; ++cc)
                *(float4*)&PsT[cg * 4 + cc][rg * 4] =
                    make_float4(nv[0][cc], nv[1][cc], nv[2][cc], nv[3][cc]);
        }
        __syncthreads();
    }

    if (jg == 0) {
        float* Ak = ACC + ((size_t)k * D2 + r0 + rg * 4) * D2;
        #pragma unroll
        for (int rr = 0; rr < 4; ++rr)
            *(float4*)&Ak[rr * D2 + cg * 4] =
                make_float4(acc[rr][0], acc[rr][1], acc[rr][2], acc[rr][3]);
    }
}

// ---------------------------------------------------------------------------
// K2: blocks 0..511 = per-batch chains (128 thr, trajectory buffered in LDS,
// barriers drain lgkm only); blocks 512+ = zero blocks, one batch-quarter
// each (1 label load, 64 NT stores, label channel skipped).
// ---------------------------------------------------------------------------
__global__ __launch_bounds__(128) void k_prop(
    const float* __restrict__ s_in, const float* __restrict__ ACC,
    const int* __restrict__ labels, float* __restrict__ out)
{
    const int bid = blockIdx.x, tid = threadIdx.x;

    if (bid >= CHAINB) {
        const int z = bid - CHAINB;            // 0..2047
        const int b = z >> 2, q = z & 3;       // batch, quarter
        const int lab = labels[b];
        const vf4 zv = {0.f, 0.f, 0.f, 0.f};
        float* bbase = out + (size_t)b * TSTEPS * K_OPS * D2
                           + (size_t)q * 16 * K_OPS * D2;
        #pragma unroll 4
        for (int s = 0; s < 16; ++s) {
            vf4* p = (vf4*)(bbase + (size_t)s * K_OPS * D2);
            #pragma unroll
            for (int qq = 0; qq < 4; ++qq) {
                const int slot = tid + qq * 128;
                if ((slot >> 5) != lab) __builtin_nontemporal_store(zv, p + slot);
            }
        }
        return;
    }

    // ---- chain path: one batch per block, thread i owns row i ----
    __shared__ float s_lds[D2];
    __shared__ float out_lds[TSTEPS][D2];   // 32 KB trajectory buffer

    const int b = bid, i = tid;
    const int lab = labels[b];

    float row[D2];
    const float4* rowp = (const float4*)(ACC + ((size_t)lab * D2 + i) * D2);
    #pragma unroll
    for (int jj = 0; jj < 32; ++jj) {
        const float4 rv = rowp[jj];
        row[4 * jj + 0] = rv.x; row[4 * jj + 1] = rv.y;
        row[4 * jj + 2] = rv.z; row[4 * jj + 3] = rv.w;
    }

    float sval = s_in[((size_t)b * K_OPS + lab) * D2 + i];
    s_lds[i] = sval;
    out_lds[0][i] = sval;
    __syncthreads();

    for (int t = 1; t < TSTEPS; ++t) {
        float acc = 0.f;
        const float4* s4 = (const float4*)s_lds;
        #pragma unroll
        for (int jj = 0; jj < 32; ++jj) {
            const float4 sv = s4[jj];
            acc = fmaf(row[4 * jj + 0], sv.x, acc);
            acc = fmaf(row[4 * jj + 1], sv.y, acc);
            acc = fmaf(row[4 * jj + 2], sv.z, acc);
            acc = fmaf(row[4 * jj + 3], sv.w, acc);
        }
        __syncthreads();              // reads of s_lds done (lgkm only)
        s_lds[i] = acc;
        out_lds[t][i] = acc;
        __syncthreads();              // new state visible (lgkm only)
    }

    // ---- bulk store: 32 KB coalesced, fire-and-forget ----
    const float* ol = &out_lds[0][0];
    float* ob = out + ((size_t)b * TSTEPS * K_OPS + lab) * D2;
    #pragma unroll
    for (int q = 0; q < 16; ++q) {
        const int s  = tid + q * 128;        // 0..2047 float4 slots
        const int t  = s >> 5;
        const int c4 = s & 31;
        const vf4 v = *(const vf4*)(ol + s * 4);
        __builtin_nontemporal_store(v, (vf4*)(ob + (size_t)t * K_OPS * D2) + c4);
    }
}

extern "C" void kernel_launch(void* const* d_in, const int* in_sizes, int n_in,
                              void* d_out, int out_size, void* d_ws, size_t ws_size,
                              hipStream_t stream) {
    const float* u_t = (const float*)d_in[0];   // [512,16]
    const float* s_t = (const float*)d_in[1];   // [512,16,128]
    const float* H   = (const float*)d_in[2];   // [16,128,128]

    float* out    = (float*)d_out;
    float* Aw     = (float*)d_ws;                       // [16,128,128] = 1 MB
    int*   labels = (int*)(Aw + K_OPS * D2 * D2);       // [512]

    hipLaunchKernelGGL(k_taylor, dim3(256), dim3(256), 0, stream,
                       H, u_t, Aw, labels);
    hipLaunchKernelGGL(k_prop, dim3(CHAINB + ZEROB), dim3(128), 0, stream,
                       s_t, Aw, labels, out);
}